// Round 13
// baseline (36.390 us; speedup 1.0000x reference)
//
#include <hip/hip_runtime.h>

#define D 64
#define K 50
#define GROUPS 8               // 8 groups x 8 lanes; one neighbor row per group per iter
#define KPAD 56                // ceil(50/8)*8
#define ITERS (KPAD / GROUPS)  // 7
#define RPB 8                  // rows per tile; each of 4 waves reduces 2 rows
#define THREADS 256
#define SLOTS (RPB * KPAD)     // 448 -> 2 slots/thread
#define AGG_BLOCKS 512         // persistent: 2048 tiles / 512 = 4 tiles per block
#define ROW_BYTES 72           // 64 B int8 + 4 B combined factor + 4 B pad

// ---------- prologue: per-row int8 quant; factor = rsqrt(deg)*rowmax/127 embedded in row
__global__ __launch_bounds__(THREADS)
void prep_q8(const float* __restrict__ emb, const float* __restrict__ deg,
             char* __restrict__ tab, float* __restrict__ rtab, int nuser)
{
    const int tid = blockIdx.x * THREADS + threadIdx.x;
    const int row = tid >> 4;
    const int sub = tid & 15;

    if (blockIdx.x == 0 && threadIdx.x < ROW_BYTES / 4)      // zero sentinel row
        ((unsigned*)(tab + (size_t)nuser * ROW_BYTES))[threadIdx.x] = 0u;

    if (row >= nuser) return;

    const float4 f = ((const float4*)emb)[row * 16 + sub];
    float m = fmaxf(fmaxf(fabsf(f.x), fabsf(f.y)), fmaxf(fabsf(f.z), fabsf(f.w)));
    #pragma unroll
    for (int off = 1; off < 16; off <<= 1)
        m = fmaxf(m, __shfl_xor(m, off));                    // rowmax in 16-lane group
    const float inv = (m > 0.0f) ? 127.0f / m : 0.0f;
    const int q0 = (int)rintf(f.x * inv);
    const int q1 = (int)rintf(f.y * inv);
    const int q2 = (int)rintf(f.z * inv);
    const int q3 = (int)rintf(f.w * inv);
    const unsigned pk = (q0 & 0xFF) | ((q1 & 0xFF) << 8) |
                        ((q2 & 0xFF) << 16) | ((unsigned)(q3 & 0xFF) << 24);
    char* rbase = tab + (size_t)row * ROW_BYTES;
    *(unsigned*)(rbase + sub * 4) = pk;
    if (sub == 0) {
        const float n = deg[row];
        const float r = (n > 0.0f) ? rsqrtf(n) : 0.0f;
        rtab[row] = r;
        *(float*)(rbase + 64) = r * m * (1.0f / 127.0f);     // neighbor factor in-row
    }
}

__device__ __forceinline__ float sb(unsigned v, int byte) {
    return (float)((int)(v << (24 - 8 * byte)) >> 24);       // sign-extend byte
}

// ---------- main: persistent blocks, double-buffered LDS id staging.
// Next tile's u_u loads issue BEFORE current tile's compute (latency hidden);
// ds_writes land after compute; one barrier per tile.
__global__ __launch_bounds__(THREADS)
void social_agg_q8(const int* __restrict__ nodes,
                   const int* __restrict__ u_u,
                   const float* __restrict__ rtab,
                   const char* __restrict__ tab,
                   float* __restrict__ out,
                   int batch, int nuser, int ntiles)
{
    __shared__ unsigned ids[2][RPB][KPAD];
    __shared__ float    cfac[2][RPB];

    const int tid  = threadIdx.x;
    const int wave = tid >> 6;
    const int lane = tid & 63;
    const int g    = lane >> 3;                      // K-group 0..7
    const int sub  = lane & 7;                       // 8 B slice of 64 B int8 data

    int tile = blockIdx.x;
    int cur  = 0;

    // ---- prologue: stage first tile directly ----
    if (tile < ntiles) {
        const int base = tile * RPB;
        for (int p = tid; p < SLOTS; p += THREADS) {
            const int r = p / KPAD, k = p - r * KPAD, row = base + r;
            unsigned nb = (unsigned)nuser;                   // sentinel row
            if (row < batch && k < K)
                nb = (unsigned)u_u[nodes[row] * K + k];
            ids[0][r][k] = nb;
        }
        if (tid < RPB) {
            const int row = base + tid;
            cfac[0][tid] = (row < batch) ? rtab[nodes[row]] : 0.0f;
        }
    }
    __syncthreads();

    for (; tile < ntiles; tile += gridDim.x) {
        const int nxt = tile + gridDim.x;

        // ---- issue next tile's staging loads into registers (hidden by compute) ----
        unsigned s_nb[2];
        float    s_cf = 0.0f;
        if (nxt < ntiles) {
            const int nbase = nxt * RPB;
            int ns = 0;
            for (int p = tid; p < SLOTS; p += THREADS) {
                const int r = p / KPAD, k = p - r * KPAD, row = nbase + r;
                unsigned nb = (unsigned)nuser;
                if (row < batch && k < K)
                    nb = (unsigned)u_u[nodes[row] * K + k];
                s_nb[ns++] = nb;
            }
            if (tid < RPB) {
                const int row = nbase + tid;
                s_cf = (row < batch) ? rtab[nodes[row]] : 0.0f;
            }
        }

        // ---- compute current tile ----
        const int base = tile * RPB;
        const int r0   = wave * 2;
        const int row0 = base + r0;

        float a0[8] = {0,0,0,0,0,0,0,0};
        float a1[8] = {0,0,0,0,0,0,0,0};
        #pragma unroll
        for (int i = 0; i < ITERS; ++i) {
            const unsigned nb0 = ids[cur][r0][i * GROUPS + g];
            const unsigned nb1 = ids[cur][r0 + 1][i * GROUPS + g];
            const char* b0 = tab + (size_t)nb0 * ROW_BYTES;
            const char* b1 = tab + (size_t)nb1 * ROW_BYTES;
            const uint2 v0 = *(const uint2*)(b0 + sub * 8);
            const uint2 v1 = *(const uint2*)(b1 + sub * 8);
            const float f0 = *(const float*)(b0 + 64);
            const float f1 = *(const float*)(b1 + 64);
            a0[0] += f0 * sb(v0.x, 0); a0[1] += f0 * sb(v0.x, 1);
            a0[2] += f0 * sb(v0.x, 2); a0[3] += f0 * sb(v0.x, 3);
            a0[4] += f0 * sb(v0.y, 0); a0[5] += f0 * sb(v0.y, 1);
            a0[6] += f0 * sb(v0.y, 2); a0[7] += f0 * sb(v0.y, 3);
            a1[0] += f1 * sb(v1.x, 0); a1[1] += f1 * sb(v1.x, 1);
            a1[2] += f1 * sb(v1.x, 2); a1[3] += f1 * sb(v1.x, 3);
            a1[4] += f1 * sb(v1.y, 0); a1[5] += f1 * sb(v1.y, 1);
            a1[6] += f1 * sb(v1.y, 2); a1[7] += f1 * sb(v1.y, 3);
        }
        #pragma unroll
        for (int off = 8; off <= 32; off <<= 1) {
            #pragma unroll
            for (int j = 0; j < 8; ++j) { a0[j] += __shfl_xor(a0[j], off);
                                          a1[j] += __shfl_xor(a1[j], off); }
        }
        if (g == 0) {
            if (row0 < batch) {
                const float c = cfac[cur][r0];
                float* o = out + (size_t)row0 * D + sub * 8;
                *(float4*)(o)     = make_float4(c*a0[0], c*a0[1], c*a0[2], c*a0[3]);
                *(float4*)(o + 4) = make_float4(c*a0[4], c*a0[5], c*a0[6], c*a0[7]);
            }
            if (row0 + 1 < batch) {
                const float c = cfac[cur][r0 + 1];
                float* o = out + (size_t)(row0 + 1) * D + sub * 8;
                *(float4*)(o)     = make_float4(c*a1[0], c*a1[1], c*a1[2], c*a1[3]);
                *(float4*)(o + 4) = make_float4(c*a1[4], c*a1[5], c*a1[6], c*a1[7]);
            }
        }

        // ---- write staged next tile into the other buffer; one barrier per tile ----
        if (nxt < ntiles) {
            int ns = 0;
            for (int p = tid; p < SLOTS; p += THREADS) {
                const int r = p / KPAD, k = p - r * KPAD;
                ids[cur ^ 1][r][k] = s_nb[ns++];
            }
            if (tid < RPB) cfac[cur ^ 1][tid] = s_cf;
        }
        __syncthreads();
        cur ^= 1;
    }
}

// ---------- fallback (fp32 single-kernel) if workspace is too small ----------
__global__ __launch_bounds__(THREADS)
void social_agg_f32(const int* __restrict__ nodes,
                    const int* __restrict__ u_u,
                    const float* __restrict__ u_u_l,
                    const float* __restrict__ emb,
                    float* __restrict__ out,
                    int batch)
{
    __shared__ uint2 nw[4][52];
    const int base = blockIdx.x * 4;
    const int p = threadIdx.x;
    if (p < 4 * 52) {
        const int r = p / 52, k = p - r * 52, row = base + r;
        int nb = 0; float w = 0.0f;
        if (row < batch && k < K) {
            const int node = nodes[row];
            const float Na = u_u_l[node];
            nb = u_u[node * K + k];
            const float prod = Na * u_u_l[nb];
            w = (prod > 0.0f) ? rsqrtf(prod) : 0.0f;
        }
        nw[r][k] = make_uint2((unsigned)nb, __float_as_uint(w));
    }
    __syncthreads();
    const int wave = threadIdx.x >> 6, lane = threadIdx.x & 63;
    const int kk = lane >> 4, sub = lane & 15, row = base + wave;
    float4 acc = make_float4(0.f, 0.f, 0.f, 0.f);
    #pragma unroll
    for (int i = 0; i < 13; ++i) {
        const uint2 e = nw[wave][i * 4 + kk];
        const float wk = __uint_as_float(e.y);
        const float4 v = *(const float4*)(emb + (size_t)e.x * D + sub * 4);
        acc.x += wk * v.x; acc.y += wk * v.y; acc.z += wk * v.z; acc.w += wk * v.w;
    }
    #pragma unroll
    for (int off = 16; off <= 32; off <<= 1) {
        acc.x += __shfl_xor(acc.x, off);
        acc.y += __shfl_xor(acc.y, off);
        acc.z += __shfl_xor(acc.z, off);
        acc.w += __shfl_xor(acc.w, off);
    }
    if (row < batch && kk == 0)
        *(float4*)(out + (size_t)row * D + sub * 4) = acc;
}

extern "C" void kernel_launch(void* const* d_in, const int* in_sizes, int n_in,
                              void* d_out, int out_size, void* d_ws, size_t ws_size,
                              hipStream_t stream) {
    const int*   nodes = (const int*)d_in[0];
    const int*   u_u   = (const int*)d_in[1];
    const float* u_u_l = (const float*)d_in[2];
    const float* emb   = (const float*)d_in[3];
    float*       out   = (float*)d_out;

    const int batch = in_sizes[0];
    const int nuser = in_sizes[1] / K;                   // N_USERS

    const size_t tab_bytes  = (size_t)(nuser + 1) * ROW_BYTES;  // +1 sentinel row
    const size_t rtab_bytes = (size_t)nuser * 4;
    if (ws_size >= tab_bytes + rtab_bytes) {
        char*  tab  = (char*)d_ws;
        float* rtab = (float*)((char*)d_ws + tab_bytes);
        const int pthreads = nuser * 16;
        const int pblocks  = (pthreads + THREADS - 1) / THREADS;
        prep_q8<<<pblocks, THREADS, 0, stream>>>(emb, u_u_l, tab, rtab, nuser);
        const int ntiles = (batch + RPB - 1) / RPB;      // 2048
        const int blocks = (ntiles < AGG_BLOCKS) ? ntiles : AGG_BLOCKS;
        social_agg_q8<<<blocks, THREADS, 0, stream>>>(nodes, u_u, rtab, tab,
                                                      out, batch, nuser, ntiles);
    } else {
        const int blocks = (batch + 3) / 4;
        social_agg_f32<<<blocks, THREADS, 0, stream>>>(nodes, u_u, u_u_l, emb,
                                                       out, batch);
    }
}

// Round 14
// 29.006 us; speedup vs baseline: 1.2546x; 1.2546x over previous
//
#include <hip/hip_runtime.h>

#define D 64
#define K 50
#define KK 4                   // 4 K-groups of 16 lanes; one neighbor row per group/iter
#define KPAD 52                // ceil(50/4)*4
#define ITERS (KPAD / KK)      // 13
#define RPB 8                  // rows per block; each of 4 waves reduces 2 rows
#define THREADS 256

// ---------- prologue: semb[u] = rsqrt(deg[u]) * emb[u] in bf16 (RNE); rtab[u] for center
__global__ __launch_bounds__(THREADS)
void prep_semb(const float* __restrict__ emb, const float* __restrict__ deg,
               unsigned* __restrict__ semb, float* __restrict__ rtab, int nuser)
{
    const int tid = blockIdx.x * THREADS + threadIdx.x;
    const int row = tid >> 4;
    const int sub = tid & 15;

    // zero the sentinel row (id == nuser): 32 uints = 128 B
    if (blockIdx.x == 0 && threadIdx.x < D / 2)
        semb[(size_t)nuser * (D / 2) + threadIdx.x] = 0u;

    if (row >= nuser) return;

    const float n = deg[row];                      // 16 lanes same addr -> broadcast
    const float r = (n > 0.0f) ? rsqrtf(n) : 0.0f;
    if (sub == 0) rtab[row] = r;

    const float4 f = ((const float4*)emb)[row * 16 + sub];
    unsigned a = __float_as_uint(f.x * r), b = __float_as_uint(f.y * r);
    unsigned c = __float_as_uint(f.z * r), d = __float_as_uint(f.w * r);
    a = (a + 0x7FFFu + ((a >> 16) & 1u)) >> 16;    // RNE bf16
    b = (b + 0x7FFFu + ((b >> 16) & 1u)) >> 16;
    c = (c + 0x7FFFu + ((c >> 16) & 1u)) >> 16;
    d = (d + 0x7FFFu + ((d >> 16) & 1u)) >> 16;
    ((uint2*)semb)[row * 16 + sub] = make_uint2(a | (b << 16), c | (d << 16));
}

// ---------- main: phase 1 = coalesced u_u ids only; phase 2 = pure unweighted
// bf16-row sum (no factor loads). 16 lanes x 8 B per 128 B row, 4 rows/instr.
__global__ __launch_bounds__(THREADS)
void social_agg_sum(const int* __restrict__ nodes,
                    const int* __restrict__ u_u,
                    const float* __restrict__ rtab,
                    const unsigned* __restrict__ semb,
                    float* __restrict__ out,
                    int batch, int nuser)
{
    __shared__ unsigned ids[RPB][KPAD];
    __shared__ float    cfac[RPB];                 // rtab[center node] per row

    const int base = blockIdx.x * RPB;

    for (int p = threadIdx.x; p < RPB * KPAD; p += THREADS) {
        const int r   = p / KPAD;
        const int k   = p - r * KPAD;
        const int row = base + r;
        unsigned nb = (unsigned)nuser;             // sentinel: zero row
        if (row < batch && k < K)
            nb = (unsigned)u_u[nodes[row] * K + k];
        ids[r][k] = nb;
    }
    if (threadIdx.x < RPB) {
        const int row = base + threadIdx.x;
        cfac[threadIdx.x] = (row < batch) ? rtab[nodes[row]] : 0.0f;
    }
    __syncthreads();

    const int wave = threadIdx.x >> 6;
    const int lane = threadIdx.x & 63;
    const int kk   = lane >> 4;                    // K-group 0..3
    const int sub  = lane & 15;                    // 8 B slice: dims sub*4..sub*4+3
    const int r0   = wave * 2;
    const int row0 = base + r0;

    float a0[4] = {0,0,0,0};
    float a1[4] = {0,0,0,0};
    #pragma unroll
    for (int i = 0; i < ITERS; ++i) {
        const unsigned nb0 = ids[r0][i * KK + kk];
        const unsigned nb1 = ids[r0 + 1][i * KK + kk];
        const uint2 v0 = *(const uint2*)(semb + (size_t)nb0 * (D / 2) + sub * 2);
        const uint2 v1 = *(const uint2*)(semb + (size_t)nb1 * (D / 2) + sub * 2);
        a0[0] += __uint_as_float(v0.x << 16);
        a0[1] += __uint_as_float(v0.x & 0xFFFF0000u);
        a0[2] += __uint_as_float(v0.y << 16);
        a0[3] += __uint_as_float(v0.y & 0xFFFF0000u);
        a1[0] += __uint_as_float(v1.x << 16);
        a1[1] += __uint_as_float(v1.x & 0xFFFF0000u);
        a1[2] += __uint_as_float(v1.y << 16);
        a1[3] += __uint_as_float(v1.y & 0xFFFF0000u);
    }

    // Reduce the 4 K-groups (lanes sub, 16+sub, 32+sub, 48+sub hold partials).
    #pragma unroll
    for (int off = 16; off <= 32; off <<= 1) {
        #pragma unroll
        for (int j = 0; j < 4; ++j) { a0[j] += __shfl_xor(a0[j], off);
                                      a1[j] += __shfl_xor(a1[j], off); }
    }

    if (kk == 0) {
        if (row0 < batch) {
            const float c = cfac[r0];
            *(float4*)(out + (size_t)row0 * D + sub * 4) =
                make_float4(c * a0[0], c * a0[1], c * a0[2], c * a0[3]);
        }
        if (row0 + 1 < batch) {
            const float c = cfac[r0 + 1];
            *(float4*)(out + (size_t)(row0 + 1) * D + sub * 4) =
                make_float4(c * a1[0], c * a1[1], c * a1[2], c * a1[3]);
        }
    }
}

// ---------- fallback (fp32 single-kernel) if workspace is too small ----------
__global__ __launch_bounds__(THREADS)
void social_agg_f32(const int* __restrict__ nodes,
                    const int* __restrict__ u_u,
                    const float* __restrict__ u_u_l,
                    const float* __restrict__ emb,
                    float* __restrict__ out,
                    int batch)
{
    __shared__ uint2 nw[4][52];
    const int base = blockIdx.x * 4;
    const int p = threadIdx.x;
    if (p < 4 * 52) {
        const int r = p / 52, k = p - r * 52, row = base + r;
        int nb = 0; float w = 0.0f;
        if (row < batch && k < K) {
            const int node = nodes[row];
            const float Na = u_u_l[node];
            nb = u_u[node * K + k];
            const float prod = Na * u_u_l[nb];
            w = (prod > 0.0f) ? rsqrtf(prod) : 0.0f;
        }
        nw[r][k] = make_uint2((unsigned)nb, __float_as_uint(w));
    }
    __syncthreads();
    const int wave = threadIdx.x >> 6, lane = threadIdx.x & 63;
    const int kk = lane >> 4, sub = lane & 15, row = base + wave;
    float4 acc = make_float4(0.f, 0.f, 0.f, 0.f);
    #pragma unroll
    for (int i = 0; i < 13; ++i) {
        const uint2 e = nw[wave][i * 4 + kk];
        const float wk = __uint_as_float(e.y);
        const float4 v = *(const float4*)(emb + (size_t)e.x * D + sub * 4);
        acc.x += wk * v.x; acc.y += wk * v.y; acc.z += wk * v.z; acc.w += wk * v.w;
    }
    #pragma unroll
    for (int off = 16; off <= 32; off <<= 1) {
        acc.x += __shfl_xor(acc.x, off);
        acc.y += __shfl_xor(acc.y, off);
        acc.z += __shfl_xor(acc.z, off);
        acc.w += __shfl_xor(acc.w, off);
    }
    if (row < batch && kk == 0)
        *(float4*)(out + (size_t)row * D + sub * 4) = acc;
}

extern "C" void kernel_launch(void* const* d_in, const int* in_sizes, int n_in,
                              void* d_out, int out_size, void* d_ws, size_t ws_size,
                              hipStream_t stream) {
    const int*   nodes = (const int*)d_in[0];
    const int*   u_u   = (const int*)d_in[1];
    const float* u_u_l = (const float*)d_in[2];
    const float* emb   = (const float*)d_in[3];
    float*       out   = (float*)d_out;

    const int batch = in_sizes[0];
    const int nuser = in_sizes[1] / K;                   // N_USERS

    const size_t semb_bytes = (size_t)(nuser + 1) * D * 2;  // bf16 rows + sentinel
    const size_t rtab_bytes = (size_t)nuser * 4;
    if (ws_size >= semb_bytes + rtab_bytes) {
        unsigned* semb = (unsigned*)d_ws;
        float*    rtab = (float*)((char*)d_ws + semb_bytes);
        const int pthreads = nuser * 16;                 // 16 lanes per row
        const int pblocks  = (pthreads + THREADS - 1) / THREADS;
        prep_semb<<<pblocks, THREADS, 0, stream>>>(emb, u_u_l, semb, rtab, nuser);
        const int blocks = (batch + RPB - 1) / RPB;
        social_agg_sum<<<blocks, THREADS, 0, stream>>>(nodes, u_u, rtab, semb,
                                                       out, batch, nuser);
    } else {
        const int blocks = (batch + 3) / 4;
        social_agg_f32<<<blocks, THREADS, 0, stream>>>(nodes, u_u, u_u_l, emb,
                                                       out, batch);
    }
}